// Round 1
// baseline (1609.014 us; speedup 1.0000x reference)
//
#include <hip/hip_runtime.h>
#include <hip/hip_bf16.h>
#include <stdint.h>

#define DI __device__ __forceinline__

typedef __attribute__((ext_vector_type(8))) __bf16 bf16x8;
typedef __attribute__((ext_vector_type(8))) unsigned short u16x8;
typedef __attribute__((ext_vector_type(4))) unsigned short u16x4;
typedef __attribute__((ext_vector_type(4))) float f32x4;

typedef __attribute__((address_space(1))) const unsigned int* gp1;
typedef __attribute__((address_space(3))) unsigned int* lp3;

static constexpr int Mdim = 8192;   // B*S
static constexpr int Kdim = 4096;   // D
static constexpr int Ndim = 16384;  // F

DI unsigned short f2bf(float f) {
  union { float f; unsigned int u; } v;
  v.f = f;
  unsigned int u = v.u;
  // round-to-nearest-even (inputs are finite random normals; no NaN handling needed)
  unsigned int r = (u + 0x7fffu + ((u >> 16) & 1u)) >> 16;
  return (unsigned short)r;
}

DI void gload_lds16(const void* g, void* l) {
  // width=16: emits global_load_lds_dwordx4; LDS dest = wave-uniform base + lane*16
  __builtin_amdgcn_global_load_lds((gp1)g, (lp3)l, 16, 0, 0);
}

// ---------------- pre-pass: A fp32 -> bf16 (elementwise) ----------------
__global__ void k_convertA(const float* __restrict__ in,
                           unsigned short* __restrict__ out, int n8) {
  int stride = gridDim.x * blockDim.x;
  for (int i = blockIdx.x * blockDim.x + threadIdx.x; i < n8; i += stride) {
    const float4* p = reinterpret_cast<const float4*>(in) + (size_t)i * 2;
    float4 a = p[0], b = p[1];
    u16x8 o;
    o[0] = f2bf(a.x); o[1] = f2bf(a.y); o[2] = f2bf(a.z); o[3] = f2bf(a.w);
    o[4] = f2bf(b.x); o[5] = f2bf(b.y); o[6] = f2bf(b.z); o[7] = f2bf(b.w);
    reinterpret_cast<u16x8*>(out)[i] = o;
  }
}

// -------- pre-pass: B (K,N) fp32 -> Bt (N,K) bf16 (LDS-tiled transpose) --------
__global__ void k_transB(const float* __restrict__ B,
                         unsigned short* __restrict__ Bt) {
  __shared__ unsigned short lds[64][68];  // +4 pad breaks bank alias
  const int n0 = blockIdx.x * 64;
  const int k0 = blockIdx.y * 64;
  const int tid = threadIdx.x;
  const int rr = tid >> 4;  // 0..15
  const int cc = tid & 15;  // 0..15
#pragma unroll
  for (int i = 0; i < 4; ++i) {
    int r = rr + i * 16;  // k within tile
    float4 v = *reinterpret_cast<const float4*>(B + (size_t)(k0 + r) * Ndim + n0 + cc * 4);
    u16x4 o;
    o[0] = f2bf(v.x); o[1] = f2bf(v.y); o[2] = f2bf(v.z); o[3] = f2bf(v.w);
    *reinterpret_cast<u16x4*>(&lds[r][cc * 4]) = o;
  }
  __syncthreads();
#pragma unroll
  for (int i = 0; i < 4; ++i) {
    int n = rr + i * 16;
    u16x4 o;
    o[0] = lds[cc * 4 + 0][n];
    o[1] = lds[cc * 4 + 1][n];
    o[2] = lds[cc * 4 + 2][n];
    o[3] = lds[cc * 4 + 3][n];
    *reinterpret_cast<u16x4*>(Bt + (size_t)(n0 + n) * Kdim + k0 + cc * 4) = o;
  }
}

// ---------------- tile mapping (XCD-aware swizzle; 8192 % 8 == 0) ----------------
DI void tile_map(int& m0, int& n0) {
  const int bid = blockIdx.x;
  const int cpx = gridDim.x >> 3;
  const int swz = (bid & 7) * cpx + (bid >> 3);
  const int mt = swz & (Mdim / 128 - 1);  // 64 m-tiles
  const int nt = swz >> 6;                // 128 n-tiles
  m0 = mt * 128;
  n0 = nt * 128;
}

// ---------------- main GEMM: A(M,K) bf16 x Bt(N,K) bf16 -> C(M,N) fp32 + bias ----------------
__global__ __launch_bounds__(256) void k_gemm(const unsigned short* __restrict__ A,
                                              const unsigned short* __restrict__ Bt,
                                              const float* __restrict__ bias,
                                              float* __restrict__ C) {
  __shared__ unsigned short lA[128 * 32];
  __shared__ unsigned short lB[128 * 32];

  const int tid = threadIdx.x;
  const int wave = tid >> 6;
  const int lane = tid & 63;
  const int lrow = lane & 15;
  const int kslc = lane >> 4;
  const int wr = wave >> 1;  // 0..1
  const int wc = wave & 1;   // 0..1

  int m0, n0;
  tile_map(m0, n0);

  f32x4 acc[4][4];
#pragma unroll
  for (int i = 0; i < 4; ++i)
#pragma unroll
    for (int j = 0; j < 4; ++j)
      acc[i][j] = f32x4{0.f, 0.f, 0.f, 0.f};

  // staging geometry: LDS [row][k] 128x32 linear; wave w covers elems [w*1024, (w+1)*1024)
  // call j: lane l -> elem e = w*1024 + j*512 + l*8 ; row = e>>5, kk = e&31
  const int e0 = wave * 1024 + lane * 8;
  const int r0 = e0 >> 5, kk0 = e0 & 31;
  const int r1 = (e0 + 512) >> 5, kk1 = (e0 + 512) & 31;

  const unsigned short* Abase = A + (size_t)m0 * Kdim;
  const unsigned short* Bbase = Bt + (size_t)n0 * Kdim;

  unsigned short* lA0 = &lA[wave * 1024];
  unsigned short* lA1 = &lA[wave * 1024 + 512];
  unsigned short* lB0 = &lB[wave * 1024];
  unsigned short* lB1 = &lB[wave * 1024 + 512];

  const int ldsA = (wr * 64 + lrow) * 32 + kslc * 8;
  const int ldsB = (wc * 64 + lrow) * 32 + kslc * 8;

  for (int k0 = 0; k0 < Kdim; k0 += 32) {
    gload_lds16(Abase + (size_t)r0 * Kdim + k0 + kk0, lA0);
    gload_lds16(Abase + (size_t)r1 * Kdim + k0 + kk1, lA1);
    gload_lds16(Bbase + (size_t)r0 * Kdim + k0 + kk0, lB0);
    gload_lds16(Bbase + (size_t)r1 * Kdim + k0 + kk1, lB1);
    __syncthreads();  // compiler drains vmcnt before s_barrier

    bf16x8 af[4], bfv[4];
#pragma unroll
    for (int m = 0; m < 4; ++m)
      af[m] = __builtin_bit_cast(bf16x8, *reinterpret_cast<const u16x8*>(&lA[ldsA + m * 16 * 32]));
#pragma unroll
    for (int n = 0; n < 4; ++n)
      bfv[n] = __builtin_bit_cast(bf16x8, *reinterpret_cast<const u16x8*>(&lB[ldsB + n * 16 * 32]));

#pragma unroll
    for (int m = 0; m < 4; ++m)
#pragma unroll
      for (int n = 0; n < 4; ++n)
        acc[m][n] = __builtin_amdgcn_mfma_f32_16x16x32_bf16(af[m], bfv[n], acc[m][n], 0, 0, 0);

    __syncthreads();
  }

  // epilogue: C/D layout col = lane&15, row = (lane>>4)*4 + reg
#pragma unroll
  for (int n = 0; n < 4; ++n) {
    const int col = n0 + wc * 64 + n * 16 + lrow;
    const float bv = bias[col];
#pragma unroll
    for (int m = 0; m < 4; ++m) {
      const int row = m0 + wr * 64 + m * 16 + kslc * 4;
      float* cp = C + (size_t)row * Ndim + col;
#pragma unroll
      for (int r = 0; r < 4; ++r)
        cp[(size_t)r * Ndim] = acc[m][n][r] + bv;
    }
  }
}

// ---------------- fallback: fused fp32->bf16 GEMM, no workspace needed ----------------
__global__ __launch_bounds__(256) void k_gemm_fused(const float* __restrict__ A,
                                                    const float* __restrict__ B,
                                                    const float* __restrict__ bias,
                                                    float* __restrict__ C) {
  __shared__ unsigned short lA[128 * 32];
  __shared__ unsigned short lB[32 * 136];  // [k][n] with pad

  const int tid = threadIdx.x;
  const int wave = tid >> 6;
  const int lane = tid & 63;
  const int lrow = lane & 15;
  const int kslc = lane >> 4;
  const int wr = wave >> 1;
  const int wc = wave & 1;

  int m0, n0;
  tile_map(m0, n0);

  f32x4 acc[4][4];
#pragma unroll
  for (int i = 0; i < 4; ++i)
#pragma unroll
    for (int j = 0; j < 4; ++j)
      acc[i][j] = f32x4{0.f, 0.f, 0.f, 0.f};

  for (int k0 = 0; k0 < Kdim; k0 += 32) {
#pragma unroll
    for (int j = 0; j < 2; ++j) {  // stage A [128][32]
      int e = (j * 256 + tid) * 8;
      int r = e >> 5, kk = e & 31;
      const float* src = A + (size_t)(m0 + r) * Kdim + k0 + kk;
      float4 v0 = *reinterpret_cast<const float4*>(src);
      float4 v1 = *reinterpret_cast<const float4*>(src + 4);
      u16x8 o;
      o[0] = f2bf(v0.x); o[1] = f2bf(v0.y); o[2] = f2bf(v0.z); o[3] = f2bf(v0.w);
      o[4] = f2bf(v1.x); o[5] = f2bf(v1.y); o[6] = f2bf(v1.z); o[7] = f2bf(v1.w);
      *reinterpret_cast<u16x8*>(&lA[e]) = o;
    }
#pragma unroll
    for (int j = 0; j < 2; ++j) {  // stage B [32][128(+8 pad)]
      int e = (j * 256 + tid) * 8;
      int r = e >> 7, c = e & 127;
      const float* src = B + (size_t)(k0 + r) * Ndim + n0 + c;
      float4 v0 = *reinterpret_cast<const float4*>(src);
      float4 v1 = *reinterpret_cast<const float4*>(src + 4);
      u16x8 o;
      o[0] = f2bf(v0.x); o[1] = f2bf(v0.y); o[2] = f2bf(v0.z); o[3] = f2bf(v0.w);
      o[4] = f2bf(v1.x); o[5] = f2bf(v1.y); o[6] = f2bf(v1.z); o[7] = f2bf(v1.w);
      *reinterpret_cast<u16x8*>(&lB[r * 136 + c]) = o;
    }
    __syncthreads();

    bf16x8 af[4], bfv[4];
#pragma unroll
    for (int m = 0; m < 4; ++m)
      af[m] = __builtin_bit_cast(
          bf16x8, *reinterpret_cast<const u16x8*>(&lA[(wr * 64 + m * 16 + lrow) * 32 + kslc * 8]));
#pragma unroll
    for (int n = 0; n < 4; ++n) {
      union { unsigned short s[8]; u16x8 v; } t;
      int col = wc * 64 + n * 16 + lrow;
#pragma unroll
      for (int i = 0; i < 8; ++i) t.s[i] = lB[(kslc * 8 + i) * 136 + col];
      bfv[n] = __builtin_bit_cast(bf16x8, t.v);
    }

#pragma unroll
    for (int m = 0; m < 4; ++m)
#pragma unroll
      for (int n = 0; n < 4; ++n)
        acc[m][n] = __builtin_amdgcn_mfma_f32_16x16x32_bf16(af[m], bfv[n], acc[m][n], 0, 0, 0);

    __syncthreads();
  }

#pragma unroll
  for (int n = 0; n < 4; ++n) {
    const int col = n0 + wc * 64 + n * 16 + lrow;
    const float bv = bias[col];
#pragma unroll
    for (int m = 0; m < 4; ++m) {
      const int row = m0 + wr * 64 + m * 16 + kslc * 4;
      float* cp = C + (size_t)row * Ndim + col;
#pragma unroll
      for (int r = 0; r < 4; ++r)
        cp[(size_t)r * Ndim] = acc[m][n][r] + bv;
    }
  }
}

extern "C" void kernel_launch(void* const* d_in, const int* in_sizes, int n_in,
                              void* d_out, int out_size, void* d_ws, size_t ws_size,
                              hipStream_t stream) {
  const float* inp = (const float*)d_in[0];   // (B,S,D) = (M,K)
  const float* ker = (const float*)d_in[1];   // (D,F)   = (K,N)
  const float* bias = (const float*)d_in[2];  // (F,)
  float* out = (float*)d_out;

  const size_t A_BYTES = (size_t)Mdim * Kdim * 2;  // 64 MiB
  const size_t B_BYTES = (size_t)Ndim * Kdim * 2;  // 128 MiB

  const int nblocks = (Mdim / 128) * (Ndim / 128);  // 8192

  if (ws_size >= A_BYTES + B_BYTES) {
    unsigned short* Abf = (unsigned short*)d_ws;
    unsigned short* Btb = (unsigned short*)((char*)d_ws + A_BYTES);
    k_convertA<<<2048, 256, 0, stream>>>(inp, Abf, Mdim * Kdim / 8);
    dim3 tg(Ndim / 64, Kdim / 64);
    k_transB<<<tg, 256, 0, stream>>>(ker, Btb);
    k_gemm<<<nblocks, 256, 0, stream>>>(Abf, Btb, bias, out);
  } else {
    k_gemm_fused<<<nblocks, 256, 0, stream>>>(inp, ker, bias, out);
  }
}

// Round 2
// 1152.568 us; speedup vs baseline: 1.3960x; 1.3960x over previous
//
#include <hip/hip_runtime.h>
#include <hip/hip_bf16.h>
#include <stdint.h>

#define DI __device__ __forceinline__

typedef __attribute__((ext_vector_type(8))) __bf16 bf16x8;
typedef __attribute__((ext_vector_type(8))) unsigned short u16x8;
typedef __attribute__((ext_vector_type(4))) unsigned short u16x4;
typedef __attribute__((ext_vector_type(4))) float f32x4;

typedef __attribute__((address_space(1))) const unsigned int* gp1;
typedef __attribute__((address_space(3))) unsigned int* lp3;

static constexpr int Mdim = 8192;   // B*S
static constexpr int Kdim = 4096;   // D
static constexpr int Ndim = 16384;  // F
static constexpr int NT = Kdim / 64;     // 64 K-tiles of BK=64
static constexpr int ROWB = Kdim * 2;    // 8192 B per bf16 row (A and Bt)
static constexpr int BUFB = 65536;       // one LDS buffer: A 32K + B 32K

DI unsigned short f2bf(float f) {
  union { float f; unsigned int u; } v;
  v.f = f;
  unsigned int u = v.u;
  unsigned int r = (u + 0x7fffu + ((u >> 16) & 1u)) >> 16;  // RNE
  return (unsigned short)r;
}

DI void gload_lds16(const void* g, void* l) {
  // width=16 -> global_load_lds_dwordx4; LDS dest = wave-uniform base + lane*16
  __builtin_amdgcn_global_load_lds((gp1)g, (lp3)l, 16, 0, 0);
}

DI bf16x8 ldfrag(const char* p) {
  return __builtin_bit_cast(bf16x8, *reinterpret_cast<const u16x8*>(p));
}

#define MFMA_(A_, B_, ACC_) \
  ACC_ = __builtin_amdgcn_mfma_f32_16x16x32_bf16(A_, B_, ACC_, 0, 0, 0)

// Stage one 128-row x 64-col bf16 half-tile (16 KiB) into a linear LDS region.
// Global source is pre-swizzled per-lane so that a swizzled READ
// (byte ^= (row&7)<<4) sees the correct data (both-sides-or-neither rule).
DI void stage_half(const char* g, int row0, int Tk, char* region, int wave, int lane) {
  const int r = wave * 16 + (lane >> 3);
  const int colx = (((lane & 7) ^ ((lane >> 3) & 7)) << 4);
  const char* src = g + (size_t)(row0 + r) * ROWB + Tk * 128 + colx;
  char* dst = region + wave * 2048;  // wave-uniform
  gload_lds16(src, dst);
  gload_lds16(src + (size_t)8 * ROWB, dst + 1024);
}

// ---------------- pre-pass: A fp32 -> bf16 ----------------
__global__ void k_convertA(const float* __restrict__ in,
                           unsigned short* __restrict__ out, int n8) {
  int stride = gridDim.x * blockDim.x;
  for (int i = blockIdx.x * blockDim.x + threadIdx.x; i < n8; i += stride) {
    const float4* p = reinterpret_cast<const float4*>(in) + (size_t)i * 2;
    float4 a = p[0], b = p[1];
    u16x8 o;
    o[0] = f2bf(a.x); o[1] = f2bf(a.y); o[2] = f2bf(a.z); o[3] = f2bf(a.w);
    o[4] = f2bf(b.x); o[5] = f2bf(b.y); o[6] = f2bf(b.z); o[7] = f2bf(b.w);
    reinterpret_cast<u16x8*>(out)[i] = o;
  }
}

// -------- pre-pass: B (K,N) fp32 -> Bt (N,K) bf16 --------
__global__ void k_transB(const float* __restrict__ B,
                         unsigned short* __restrict__ Bt) {
  __shared__ unsigned short lds[64][68];
  const int n0 = blockIdx.x * 64;
  const int k0 = blockIdx.y * 64;
  const int tid = threadIdx.x;
  const int rr = tid >> 4;
  const int cc = tid & 15;
#pragma unroll
  for (int i = 0; i < 4; ++i) {
    int r = rr + i * 16;
    float4 v = *reinterpret_cast<const float4*>(B + (size_t)(k0 + r) * Ndim + n0 + cc * 4);
    u16x4 o;
    o[0] = f2bf(v.x); o[1] = f2bf(v.y); o[2] = f2bf(v.z); o[3] = f2bf(v.w);
    *reinterpret_cast<u16x4*>(&lds[r][cc * 4]) = o;
  }
  __syncthreads();
#pragma unroll
  for (int i = 0; i < 4; ++i) {
    int n = rr + i * 16;
    u16x4 o;
    o[0] = lds[cc * 4 + 0][n];
    o[1] = lds[cc * 4 + 1][n];
    o[2] = lds[cc * 4 + 2][n];
    o[3] = lds[cc * 4 + 3][n];
    *reinterpret_cast<u16x4*>(Bt + (size_t)(n0 + n) * Kdim + k0 + cc * 4) = o;
  }
}

// ---------------- 256x256 8-phase GEMM ----------------
// A(M,K) bf16 x Bt(N,K) bf16 -> C(M,N) fp32 + bias
// 512 threads = 8 waves (2M x 4N); per-wave output 128x64.
// LDS per buffer: A [256][64] @0, B [256][64] @32768; double-buffered (128 KiB).
__global__ __launch_bounds__(512, 2) void k_gemm8(const unsigned short* __restrict__ A,
                                                  const unsigned short* __restrict__ Bt,
                                                  const float* __restrict__ bias,
                                                  float* __restrict__ C) {
  extern __shared__ char sm[];
  const int tid = threadIdx.x;
  const int wave = tid >> 6, lane = tid & 63;
  const int wm = wave >> 2, wn = wave & 3;
  const int lrow = lane & 15, khi = lane >> 4;

  int m0, n0;
  {
    int bid = blockIdx.x;
    int swz = (bid & 7) * (gridDim.x >> 3) + (bid >> 3);  // XCD-aware; 2048 % 8 == 0
    m0 = (swz & 31) * 256;   // 32 m-tiles
    n0 = (swz >> 5) * 256;   // 64 n-tiles
  }

  const char* Ag = (const char*)A;
  const char* Bg = (const char*)Bt;

  // swizzled within-row k-offsets for the two K=32 steps of a BK=64 tile
  const int kofs0 = (khi * 16) ^ ((lane & 7) << 4);
  const int kofs1 = (64 + khi * 16) ^ ((lane & 7) << 4);
  const int aoff = (wm * 128 + lrow) * 128;           // A frag row base (bytes)
  const int boff = 32768 + (wn * 64 + lrow) * 128;    // B frag row base (bytes)

  f32x4 acc[8][4];
#pragma unroll
  for (int i = 0; i < 8; ++i)
#pragma unroll
    for (int j = 0; j < 4; ++j) acc[i][j] = f32x4{0.f, 0.f, 0.f, 0.f};

  // ---- prologue: tile0 (A0,A1,B0,B1) + tile1 (B0,B1); leave tile1.B in flight
  stage_half(Ag, m0,       0, sm + 0,            wave, lane);
  stage_half(Ag, m0 + 128, 0, sm + 16384,        wave, lane);
  stage_half(Bg, n0,       0, sm + 32768,        wave, lane);
  stage_half(Bg, n0 + 128, 0, sm + 49152,        wave, lane);
  stage_half(Bg, n0,       1, sm + BUFB + 32768, wave, lane);
  stage_half(Bg, n0 + 128, 1, sm + BUFB + 49152, wave, lane);
  asm volatile("s_waitcnt vmcnt(4)" ::: "memory");
  __builtin_amdgcn_sched_barrier(0);
  __builtin_amdgcn_s_barrier();

  for (int T = 0; T < NT; ++T) {
    char* buf  = sm + (T & 1) * BUFB;
    char* bufN = sm + ((T + 1) & 1) * BUFB;

    // ===== phase 1: all 8 B frags + A m={0,1}; prefetch (T+1).A0 =====
    bf16x8 b00 = ldfrag(buf + boff + 0 * 2048 + kofs0);
    bf16x8 b01 = ldfrag(buf + boff + 0 * 2048 + kofs1);
    bf16x8 b10 = ldfrag(buf + boff + 1 * 2048 + kofs0);
    bf16x8 b11 = ldfrag(buf + boff + 1 * 2048 + kofs1);
    bf16x8 b20 = ldfrag(buf + boff + 2 * 2048 + kofs0);
    bf16x8 b21 = ldfrag(buf + boff + 2 * 2048 + kofs1);
    bf16x8 b30 = ldfrag(buf + boff + 3 * 2048 + kofs0);
    bf16x8 b31 = ldfrag(buf + boff + 3 * 2048 + kofs1);
    bf16x8 aX0 = ldfrag(buf + aoff + 0 * 2048 + kofs0);
    bf16x8 aX1 = ldfrag(buf + aoff + 0 * 2048 + kofs1);
    bf16x8 aY0 = ldfrag(buf + aoff + 1 * 2048 + kofs0);
    bf16x8 aY1 = ldfrag(buf + aoff + 1 * 2048 + kofs1);
    if (T + 1 < NT) stage_half(Ag, m0, T + 1, bufN, wave, lane);
    __builtin_amdgcn_s_barrier();
    __builtin_amdgcn_s_setprio(1);
    MFMA_(aX0, b00, acc[0][0]); MFMA_(aX1, b01, acc[0][0]);
    MFMA_(aY0, b00, acc[1][0]); MFMA_(aY1, b01, acc[1][0]);
    MFMA_(aX0, b10, acc[0][1]); MFMA_(aX1, b11, acc[0][1]);
    MFMA_(aY0, b10, acc[1][1]); MFMA_(aY1, b11, acc[1][1]);
    MFMA_(aX0, b20, acc[0][2]); MFMA_(aX1, b21, acc[0][2]);
    MFMA_(aY0, b20, acc[1][2]); MFMA_(aY1, b21, acc[1][2]);
    MFMA_(aX0, b30, acc[0][3]); MFMA_(aX1, b31, acc[0][3]);
    MFMA_(aY0, b30, acc[1][3]); MFMA_(aY1, b31, acc[1][3]);
    __builtin_amdgcn_s_setprio(0);
    __builtin_amdgcn_s_barrier();

    // ===== phase 2: A m={2,3}; prefetch (T+1).A1 =====
    aX0 = ldfrag(buf + aoff + 2 * 2048 + kofs0);
    aX1 = ldfrag(buf + aoff + 2 * 2048 + kofs1);
    aY0 = ldfrag(buf + aoff + 3 * 2048 + kofs0);
    aY1 = ldfrag(buf + aoff + 3 * 2048 + kofs1);
    if (T + 1 < NT) stage_half(Ag, m0 + 128, T + 1, bufN + 16384, wave, lane);
    __builtin_amdgcn_s_barrier();
    __builtin_amdgcn_s_setprio(1);
    MFMA_(aX0, b00, acc[2][0]); MFMA_(aX1, b01, acc[2][0]);
    MFMA_(aY0, b00, acc[3][0]); MFMA_(aY1, b01, acc[3][0]);
    MFMA_(aX0, b10, acc[2][1]); MFMA_(aX1, b11, acc[2][1]);
    MFMA_(aY0, b10, acc[3][1]); MFMA_(aY1, b11, acc[3][1]);
    MFMA_(aX0, b20, acc[2][2]); MFMA_(aX1, b21, acc[2][2]);
    MFMA_(aY0, b20, acc[3][2]); MFMA_(aY1, b21, acc[3][2]);
    MFMA_(aX0, b30, acc[2][3]); MFMA_(aX1, b31, acc[2][3]);
    MFMA_(aY0, b30, acc[3][3]); MFMA_(aY1, b31, acc[3][3]);
    __builtin_amdgcn_s_setprio(0);
    __builtin_amdgcn_s_barrier();

    // ===== phase 3: A m={4,5}; prefetch (T+2).B0 (B region of buf is free) =====
    aX0 = ldfrag(buf + aoff + 4 * 2048 + kofs0);
    aX1 = ldfrag(buf + aoff + 4 * 2048 + kofs1);
    aY0 = ldfrag(buf + aoff + 5 * 2048 + kofs0);
    aY1 = ldfrag(buf + aoff + 5 * 2048 + kofs1);
    if (T + 2 < NT) stage_half(Bg, n0, T + 2, buf + 32768, wave, lane);
    __builtin_amdgcn_s_barrier();
    __builtin_amdgcn_s_setprio(1);
    MFMA_(aX0, b00, acc[4][0]); MFMA_(aX1, b01, acc[4][0]);
    MFMA_(aY0, b00, acc[5][0]); MFMA_(aY1, b01, acc[5][0]);
    MFMA_(aX0, b10, acc[4][1]); MFMA_(aX1, b11, acc[4][1]);
    MFMA_(aY0, b10, acc[5][1]); MFMA_(aY1, b11, acc[5][1]);
    MFMA_(aX0, b20, acc[4][2]); MFMA_(aX1, b21, acc[4][2]);
    MFMA_(aY0, b20, acc[5][2]); MFMA_(aY1, b21, acc[5][2]);
    MFMA_(aX0, b30, acc[4][3]); MFMA_(aX1, b31, acc[4][3]);
    MFMA_(aY0, b30, acc[5][3]); MFMA_(aY1, b31, acc[5][3]);
    __builtin_amdgcn_s_setprio(0);
    __builtin_amdgcn_s_barrier();

    // ===== phase 4: A m={6,7}; prefetch (T+2).B1; counted-vmcnt boundary =====
    aX0 = ldfrag(buf + aoff + 6 * 2048 + kofs0);
    aX1 = ldfrag(buf + aoff + 6 * 2048 + kofs1);
    aY0 = ldfrag(buf + aoff + 7 * 2048 + kofs0);
    aY1 = ldfrag(buf + aoff + 7 * 2048 + kofs1);
    if (T + 2 < NT) stage_half(Bg, n0 + 128, T + 2, buf + 49152, wave, lane);
    __builtin_amdgcn_s_barrier();
    __builtin_amdgcn_s_setprio(1);
    MFMA_(aX0, b00, acc[6][0]); MFMA_(aX1, b01, acc[6][0]);
    MFMA_(aY0, b00, acc[7][0]); MFMA_(aY1, b01, acc[7][0]);
    MFMA_(aX0, b10, acc[6][1]); MFMA_(aX1, b11, acc[6][1]);
    MFMA_(aY0, b10, acc[7][1]); MFMA_(aY1, b11, acc[7][1]);
    MFMA_(aX0, b20, acc[6][2]); MFMA_(aX1, b21, acc[6][2]);
    MFMA_(aY0, b20, acc[7][2]); MFMA_(aY1, b21, acc[7][2]);
    MFMA_(aX0, b30, acc[6][3]); MFMA_(aX1, b31, acc[6][3]);
    MFMA_(aY0, b30, acc[7][3]); MFMA_(aY1, b31, acc[7][3]);
    __builtin_amdgcn_s_setprio(0);
    // boundary: everything the next tile needs is >=5 loads old; only the
    // (T+2).B half-tiles (4 loads, issued ph3/ph4) may stay in flight.
    if (T + 2 < NT) {
      asm volatile("s_waitcnt vmcnt(4)" ::: "memory");
    } else {
      asm volatile("s_waitcnt vmcnt(0)" ::: "memory");
    }
    __builtin_amdgcn_sched_barrier(0);
    __builtin_amdgcn_s_barrier();
  }

  // ---- epilogue: C/D layout col=lane&15, row=(lane>>4)*4+reg ----
#pragma unroll
  for (int n = 0; n < 4; ++n) {
    const int col = n0 + wn * 64 + n * 16 + lrow;
    const float bv = bias[col];
#pragma unroll
    for (int m = 0; m < 8; ++m) {
      const int row = m0 + wm * 128 + m * 16 + khi * 4;
      float* cp = C + (size_t)row * Ndim + col;
#pragma unroll
      for (int r = 0; r < 4; ++r)
        cp[(size_t)r * Ndim] = acc[m][n][r] + bv;
    }
  }
}

// ---------------- fallback: fused fp32->bf16 GEMM (no workspace) ----------------
__global__ __launch_bounds__(256) void k_gemm_fused(const float* __restrict__ A,
                                                    const float* __restrict__ B,
                                                    const float* __restrict__ bias,
                                                    float* __restrict__ C) {
  __shared__ unsigned short lA[128 * 32];
  __shared__ unsigned short lB[32 * 136];

  const int tid = threadIdx.x;
  const int wave = tid >> 6;
  const int lane = tid & 63;
  const int lrow = lane & 15;
  const int kslc = lane >> 4;
  const int wr = wave >> 1;
  const int wc = wave & 1;

  const int bid = blockIdx.x;
  const int cpx = gridDim.x >> 3;
  const int swz = (bid & 7) * cpx + (bid >> 3);
  const int m0 = (swz & 63) * 128;
  const int n0 = (swz >> 6) * 128;

  f32x4 acc[4][4];
#pragma unroll
  for (int i = 0; i < 4; ++i)
#pragma unroll
    for (int j = 0; j < 4; ++j) acc[i][j] = f32x4{0.f, 0.f, 0.f, 0.f};

  for (int k0 = 0; k0 < Kdim; k0 += 32) {
#pragma unroll
    for (int j = 0; j < 2; ++j) {
      int e = (j * 256 + tid) * 8;
      int r = e >> 5, kk = e & 31;
      const float* src = A + (size_t)(m0 + r) * Kdim + k0 + kk;
      float4 v0 = *reinterpret_cast<const float4*>(src);
      float4 v1 = *reinterpret_cast<const float4*>(src + 4);
      u16x8 o;
      o[0] = f2bf(v0.x); o[1] = f2bf(v0.y); o[2] = f2bf(v0.z); o[3] = f2bf(v0.w);
      o[4] = f2bf(v1.x); o[5] = f2bf(v1.y); o[6] = f2bf(v1.z); o[7] = f2bf(v1.w);
      *reinterpret_cast<u16x8*>(&lA[e]) = o;
    }
#pragma unroll
    for (int j = 0; j < 2; ++j) {
      int e = (j * 256 + tid) * 8;
      int r = e >> 7, c = e & 127;
      const float* src = B + (size_t)(k0 + r) * Ndim + n0 + c;
      float4 v0 = *reinterpret_cast<const float4*>(src);
      float4 v1 = *reinterpret_cast<const float4*>(src + 4);
      u16x8 o;
      o[0] = f2bf(v0.x); o[1] = f2bf(v0.y); o[2] = f2bf(v0.z); o[3] = f2bf(v0.w);
      o[4] = f2bf(v1.x); o[5] = f2bf(v1.y); o[6] = f2bf(v1.z); o[7] = f2bf(v1.w);
      *reinterpret_cast<u16x8*>(&lB[r * 136 + c]) = o;
    }
    __syncthreads();

    bf16x8 af[4], bfv[4];
#pragma unroll
    for (int m = 0; m < 4; ++m)
      af[m] = __builtin_bit_cast(
          bf16x8, *reinterpret_cast<const u16x8*>(&lA[(wr * 64 + m * 16 + lrow) * 32 + kslc * 8]));
#pragma unroll
    for (int n = 0; n < 4; ++n) {
      union { unsigned short s[8]; u16x8 v; } t;
      int col = wc * 64 + n * 16 + lrow;
#pragma unroll
      for (int i = 0; i < 8; ++i) t.s[i] = lB[(kslc * 8 + i) * 136 + col];
      bfv[n] = __builtin_bit_cast(bf16x8, t.v);
    }

#pragma unroll
    for (int m = 0; m < 4; ++m)
#pragma unroll
      for (int n = 0; n < 4; ++n)
        acc[m][n] = __builtin_amdgcn_mfma_f32_16x16x32_bf16(af[m], bfv[n], acc[m][n], 0, 0, 0);

    __syncthreads();
  }

#pragma unroll
  for (int n = 0; n < 4; ++n) {
    const int col = n0 + wc * 64 + n * 16 + lrow;
    const float bv = bias[col];
#pragma unroll
    for (int m = 0; m < 4; ++m) {
      const int row = m0 + wr * 64 + m * 16 + kslc * 4;
      float* cp = C + (size_t)row * Ndim + col;
#pragma unroll
      for (int r = 0; r < 4; ++r)
        cp[(size_t)r * Ndim] = acc[m][n][r] + bv;
    }
  }
}

extern "C" void kernel_launch(void* const* d_in, const int* in_sizes, int n_in,
                              void* d_out, int out_size, void* d_ws, size_t ws_size,
                              hipStream_t stream) {
  const float* inp = (const float*)d_in[0];
  const float* ker = (const float*)d_in[1];
  const float* bias = (const float*)d_in[2];
  float* out = (float*)d_out;

  const size_t A_BYTES = (size_t)Mdim * Kdim * 2;  // 64 MiB
  const size_t B_BYTES = (size_t)Ndim * Kdim * 2;  // 128 MiB

  if (ws_size >= A_BYTES + B_BYTES) {
    unsigned short* Abf = (unsigned short*)d_ws;
    unsigned short* Btb = (unsigned short*)((char*)d_ws + A_BYTES);
    k_convertA<<<2048, 256, 0, stream>>>(inp, Abf, Mdim * Kdim / 8);
    dim3 tg(Ndim / 64, Kdim / 64);
    k_transB<<<tg, 256, 0, stream>>>(ker, Btb);
    (void)hipFuncSetAttribute((const void*)k_gemm8,
                              hipFuncAttributeMaxDynamicSharedMemorySize, 131072);
    const int nblocks = (Mdim / 256) * (Ndim / 256);  // 2048
    k_gemm8<<<nblocks, 512, 131072, stream>>>(Abf, Btb, bias, out);
  } else {
    const int nblocks = (Mdim / 128) * (Ndim / 128);
    k_gemm_fused<<<nblocks, 256, 0, stream>>>(inp, ker, bias, out);
  }
}

// Round 3
// 1135.071 us; speedup vs baseline: 1.4175x; 1.0154x over previous
//
#include <hip/hip_runtime.h>
#include <hip/hip_bf16.h>
#include <stdint.h>

#define DI __device__ __forceinline__

typedef __attribute__((ext_vector_type(8))) __bf16 bf16x8;
typedef __attribute__((ext_vector_type(8))) unsigned short u16x8;
typedef __attribute__((ext_vector_type(4))) unsigned short u16x4;
typedef __attribute__((ext_vector_type(4))) float f32x4;

typedef __attribute__((address_space(1))) const unsigned int* gp1;
typedef __attribute__((address_space(3))) unsigned int* lp3;

static constexpr int Mdim = 8192;   // B*S
static constexpr int Kdim = 4096;   // D
static constexpr int Ndim = 16384;  // F
static constexpr int NT = Kdim / 64;     // 64 K-tiles of BK=64
static constexpr int ROWB = Kdim * 2;    // 8192 B per bf16 row (A and Bt)
static constexpr int BUFB = 65536;       // one LDS buffer: A 32K + B 32K

DI unsigned short f2bf(float f) {
  union { float f; unsigned int u; } v;
  v.f = f;
  unsigned int u = v.u;
  unsigned int r = (u + 0x7fffu + ((u >> 16) & 1u)) >> 16;  // RNE
  return (unsigned short)r;
}

DI void gload_lds16(const void* g, void* l) {
  // width=16 -> global_load_lds_dwordx4; LDS dest = wave-uniform base + lane*16
  __builtin_amdgcn_global_load_lds((gp1)g, (lp3)l, 16, 0, 0);
}

DI bf16x8 ldfrag(const char* p) {
  return __builtin_bit_cast(bf16x8, *reinterpret_cast<const u16x8*>(p));
}

#define MFMA_(A_, B_, ACC_) \
  ACC_ = __builtin_amdgcn_mfma_f32_16x16x32_bf16(A_, B_, ACC_, 0, 0, 0)

// 16-MFMA cluster: two m-rows (M0_,M1_) x 4 n-cols x K=64, setprio-wrapped.
#define PHASE16(A0_, A1_, A2_, A3_, M0_, M1_)                         \
  __builtin_amdgcn_s_setprio(1);                                      \
  MFMA_(A0_, b00, acc[M0_][0]); MFMA_(A1_, b01, acc[M0_][0]);         \
  MFMA_(A2_, b00, acc[M1_][0]); MFMA_(A3_, b01, acc[M1_][0]);         \
  MFMA_(A0_, b10, acc[M0_][1]); MFMA_(A1_, b11, acc[M0_][1]);         \
  MFMA_(A2_, b10, acc[M1_][1]); MFMA_(A3_, b11, acc[M1_][1]);         \
  MFMA_(A0_, b20, acc[M0_][2]); MFMA_(A1_, b21, acc[M0_][2]);         \
  MFMA_(A2_, b20, acc[M1_][2]); MFMA_(A3_, b21, acc[M1_][2]);         \
  MFMA_(A0_, b30, acc[M0_][3]); MFMA_(A1_, b31, acc[M0_][3]);         \
  MFMA_(A2_, b30, acc[M1_][3]); MFMA_(A3_, b31, acc[M1_][3]);         \
  __builtin_amdgcn_s_setprio(0)

// Stage one 128-row x 64-col bf16 half-tile (16 KiB) into a linear LDS region.
// Global source is pre-swizzled per-lane so that a swizzled READ
// (byte ^= (row&7)<<4) sees the correct data (both-sides-or-neither rule).
DI void stage_half(const char* g, int row0, int Tk, char* region, int wave, int lane) {
  const int r = wave * 16 + (lane >> 3);
  const int colx = (((lane & 7) ^ ((lane >> 3) & 7)) << 4);
  const char* src = g + (size_t)(row0 + r) * ROWB + Tk * 128 + colx;
  char* dst = region + wave * 2048;  // wave-uniform
  gload_lds16(src, dst);
  gload_lds16(src + (size_t)8 * ROWB, dst + 1024);
}

// ---------------- pre-pass: A fp32 -> bf16 ----------------
__global__ void k_convertA(const float* __restrict__ in,
                           unsigned short* __restrict__ out, int n8) {
  int stride = gridDim.x * blockDim.x;
  for (int i = blockIdx.x * blockDim.x + threadIdx.x; i < n8; i += stride) {
    const float4* p = reinterpret_cast<const float4*>(in) + (size_t)i * 2;
    float4 a = p[0], b = p[1];
    u16x8 o;
    o[0] = f2bf(a.x); o[1] = f2bf(a.y); o[2] = f2bf(a.z); o[3] = f2bf(a.w);
    o[4] = f2bf(b.x); o[5] = f2bf(b.y); o[6] = f2bf(b.z); o[7] = f2bf(b.w);
    reinterpret_cast<u16x8*>(out)[i] = o;
  }
}

// -------- pre-pass: B (K,N) fp32 -> Bt (N,K) bf16 --------
__global__ void k_transB(const float* __restrict__ B,
                         unsigned short* __restrict__ Bt) {
  __shared__ unsigned short lds[64][68];
  const int n0 = blockIdx.x * 64;
  const int k0 = blockIdx.y * 64;
  const int tid = threadIdx.x;
  const int rr = tid >> 4;
  const int cc = tid & 15;
#pragma unroll
  for (int i = 0; i < 4; ++i) {
    int r = rr + i * 16;
    float4 v = *reinterpret_cast<const float4*>(B + (size_t)(k0 + r) * Ndim + n0 + cc * 4);
    u16x4 o;
    o[0] = f2bf(v.x); o[1] = f2bf(v.y); o[2] = f2bf(v.z); o[3] = f2bf(v.w);
    *reinterpret_cast<u16x4*>(&lds[r][cc * 4]) = o;
  }
  __syncthreads();
#pragma unroll
  for (int i = 0; i < 4; ++i) {
    int n = rr + i * 16;
    u16x4 o;
    o[0] = lds[cc * 4 + 0][n];
    o[1] = lds[cc * 4 + 1][n];
    o[2] = lds[cc * 4 + 2][n];
    o[3] = lds[cc * 4 + 3][n];
    *reinterpret_cast<u16x4*>(Bt + (size_t)(n0 + n) * Kdim + k0 + cc * 4) = o;
  }
}

// ---------------- 256x256 GEMM, 2-barrier/tile pipelined schedule ----------------
// A(M,K) bf16 x Bt(N,K) bf16 -> C(M,N) fp32 + bias
// 512 threads = 8 waves (2M x 4N); per-wave output 128x64.
// LDS per buffer: A [256][64] @0, B [256][64] @32768; double-buffered (128 KiB).
__global__ __launch_bounds__(512, 2) void k_gemm8(const unsigned short* __restrict__ A,
                                                  const unsigned short* __restrict__ Bt,
                                                  const float* __restrict__ bias,
                                                  float* __restrict__ C) {
  extern __shared__ char sm[];
  const int tid = threadIdx.x;
  const int wave = tid >> 6, lane = tid & 63;
  const int wm = wave >> 2, wn = wave & 3;
  const int lrow = lane & 15, khi = lane >> 4;

  int m0, n0;
  {
    int bid = blockIdx.x;
    int swz = (bid & 7) * (gridDim.x >> 3) + (bid >> 3);  // XCD-aware; 2048 % 8 == 0
    m0 = (swz & 31) * 256;   // 32 m-tiles
    n0 = (swz >> 5) * 256;   // 64 n-tiles
  }

  const char* Ag = (const char*)A;
  const char* Bg = (const char*)Bt;

  // swizzled within-row k-offsets for the two K=32 steps of a BK=64 tile
  const int kofs0 = (khi * 16) ^ ((lane & 7) << 4);
  const int kofs1 = (64 + khi * 16) ^ ((lane & 7) << 4);
  const int aoff = (wm * 128 + lrow) * 128;           // A frag row base (bytes)
  const int boff = 32768 + (wn * 64 + lrow) * 128;    // B frag row base (bytes)

  f32x4 acc[8][4];
#pragma unroll
  for (int i = 0; i < 8; ++i)
#pragma unroll
    for (int j = 0; j < 4; ++j) acc[i][j] = f32x4{0.f, 0.f, 0.f, 0.f};

  // ---- prologue: tile0 full + tile1 B; leave tile1.B (4 loads) in flight
  stage_half(Ag, m0,       0, sm + 0,            wave, lane);
  stage_half(Ag, m0 + 128, 0, sm + 16384,        wave, lane);
  stage_half(Bg, n0,       0, sm + 32768,        wave, lane);
  stage_half(Bg, n0 + 128, 0, sm + 49152,        wave, lane);
  stage_half(Bg, n0,       1, sm + BUFB + 32768, wave, lane);
  stage_half(Bg, n0 + 128, 1, sm + BUFB + 49152, wave, lane);
  asm volatile("s_waitcnt vmcnt(4)" ::: "memory");
  __builtin_amdgcn_sched_barrier(0);
  __builtin_amdgcn_s_barrier();

  // ---- steady tiles: T in [0, NT-3]; stages A(T+1), B(T+2) unconditionally
  for (int T = 0; T < NT - 2; ++T) {
    char* buf  = sm + (T & 1) * BUFB;
    char* bufN = sm + ((T + 1) & 1) * BUFB;

    // tile-start reads: this tile's first A pair + all 8 B frags
    bf16x8 aA0 = ldfrag(buf + aoff + 0 * 2048 + kofs0);
    bf16x8 aA1 = ldfrag(buf + aoff + 0 * 2048 + kofs1);
    bf16x8 aA2 = ldfrag(buf + aoff + 1 * 2048 + kofs0);
    bf16x8 aA3 = ldfrag(buf + aoff + 1 * 2048 + kofs1);
    bf16x8 b00 = ldfrag(buf + boff + 0 * 2048 + kofs0);
    bf16x8 b01 = ldfrag(buf + boff + 0 * 2048 + kofs1);
    bf16x8 b10 = ldfrag(buf + boff + 1 * 2048 + kofs0);
    bf16x8 b11 = ldfrag(buf + boff + 1 * 2048 + kofs1);
    bf16x8 b20 = ldfrag(buf + boff + 2 * 2048 + kofs0);
    bf16x8 b21 = ldfrag(buf + boff + 2 * 2048 + kofs1);
    bf16x8 b30 = ldfrag(buf + boff + 3 * 2048 + kofs0);
    bf16x8 b31 = ldfrag(buf + boff + 3 * 2048 + kofs1);
    stage_half(Ag, m0, T + 1, bufN, wave, lane);                 // A0(T+1)
    // pre-issue next phase's A frags
    bf16x8 aB0 = ldfrag(buf + aoff + 2 * 2048 + kofs0);
    bf16x8 aB1 = ldfrag(buf + aoff + 2 * 2048 + kofs1);
    bf16x8 aB2 = ldfrag(buf + aoff + 3 * 2048 + kofs0);
    bf16x8 aB3 = ldfrag(buf + aoff + 3 * 2048 + kofs1);
    PHASE16(aA0, aA1, aA2, aA3, 0, 1);
    __builtin_amdgcn_sched_barrier(0);
    __builtin_amdgcn_s_barrier();  // mid: all waves' b-frag reads drained

    stage_half(Ag, m0 + 128, T + 1, bufN + 16384, wave, lane);   // A1(T+1)
    stage_half(Bg, n0,       T + 2, buf + 32768,  wave, lane);   // B0(T+2)
    aA0 = ldfrag(buf + aoff + 4 * 2048 + kofs0);
    aA1 = ldfrag(buf + aoff + 4 * 2048 + kofs1);
    aA2 = ldfrag(buf + aoff + 5 * 2048 + kofs0);
    aA3 = ldfrag(buf + aoff + 5 * 2048 + kofs1);
    PHASE16(aB0, aB1, aB2, aB3, 2, 3);

    stage_half(Bg, n0 + 128, T + 2, buf + 49152, wave, lane);    // B1(T+2)
    aB0 = ldfrag(buf + aoff + 6 * 2048 + kofs0);
    aB1 = ldfrag(buf + aoff + 6 * 2048 + kofs1);
    aB2 = ldfrag(buf + aoff + 7 * 2048 + kofs0);
    aB3 = ldfrag(buf + aoff + 7 * 2048 + kofs1);
    PHASE16(aA0, aA1, aA2, aA3, 4, 5);

    // drain A(T+1)+B(T+1) (8 oldest); keep B(T+2) (4 newest) in flight
    asm volatile("s_waitcnt vmcnt(4)" ::: "memory");
    __builtin_amdgcn_sched_barrier(0);
    PHASE16(aB0, aB1, aB2, aB3, 6, 7);
    __builtin_amdgcn_s_barrier();  // exit
  }

  // ---- tile NT-2: stages A(NT-1) only; full drain at end
  {
    char* buf  = sm + ((NT - 2) & 1) * BUFB;
    char* bufN = sm + ((NT - 1) & 1) * BUFB;

    bf16x8 aA0 = ldfrag(buf + aoff + 0 * 2048 + kofs0);
    bf16x8 aA1 = ldfrag(buf + aoff + 0 * 2048 + kofs1);
    bf16x8 aA2 = ldfrag(buf + aoff + 1 * 2048 + kofs0);
    bf16x8 aA3 = ldfrag(buf + aoff + 1 * 2048 + kofs1);
    bf16x8 b00 = ldfrag(buf + boff + 0 * 2048 + kofs0);
    bf16x8 b01 = ldfrag(buf + boff + 0 * 2048 + kofs1);
    bf16x8 b10 = ldfrag(buf + boff + 1 * 2048 + kofs0);
    bf16x8 b11 = ldfrag(buf + boff + 1 * 2048 + kofs1);
    bf16x8 b20 = ldfrag(buf + boff + 2 * 2048 + kofs0);
    bf16x8 b21 = ldfrag(buf + boff + 2 * 2048 + kofs1);
    bf16x8 b30 = ldfrag(buf + boff + 3 * 2048 + kofs0);
    bf16x8 b31 = ldfrag(buf + boff + 3 * 2048 + kofs1);
    stage_half(Ag, m0, NT - 1, bufN, wave, lane);
    bf16x8 aB0 = ldfrag(buf + aoff + 2 * 2048 + kofs0);
    bf16x8 aB1 = ldfrag(buf + aoff + 2 * 2048 + kofs1);
    bf16x8 aB2 = ldfrag(buf + aoff + 3 * 2048 + kofs0);
    bf16x8 aB3 = ldfrag(buf + aoff + 3 * 2048 + kofs1);
    PHASE16(aA0, aA1, aA2, aA3, 0, 1);
    __builtin_amdgcn_sched_barrier(0);
    __builtin_amdgcn_s_barrier();

    stage_half(Ag, m0 + 128, NT - 1, bufN + 16384, wave, lane);
    aA0 = ldfrag(buf + aoff + 4 * 2048 + kofs0);
    aA1 = ldfrag(buf + aoff + 4 * 2048 + kofs1);
    aA2 = ldfrag(buf + aoff + 5 * 2048 + kofs0);
    aA3 = ldfrag(buf + aoff + 5 * 2048 + kofs1);
    PHASE16(aB0, aB1, aB2, aB3, 2, 3);

    aB0 = ldfrag(buf + aoff + 6 * 2048 + kofs0);
    aB1 = ldfrag(buf + aoff + 6 * 2048 + kofs1);
    aB2 = ldfrag(buf + aoff + 7 * 2048 + kofs0);
    aB3 = ldfrag(buf + aoff + 7 * 2048 + kofs1);
    PHASE16(aA0, aA1, aA2, aA3, 4, 5);

    asm volatile("s_waitcnt vmcnt(0)" ::: "memory");
    __builtin_amdgcn_sched_barrier(0);
    PHASE16(aB0, aB1, aB2, aB3, 6, 7);
    __builtin_amdgcn_s_barrier();
  }

  // ---- tile NT-1: compute only
  {
    char* buf = sm + ((NT - 1) & 1) * BUFB;

    bf16x8 aA0 = ldfrag(buf + aoff + 0 * 2048 + kofs0);
    bf16x8 aA1 = ldfrag(buf + aoff + 0 * 2048 + kofs1);
    bf16x8 aA2 = ldfrag(buf + aoff + 1 * 2048 + kofs0);
    bf16x8 aA3 = ldfrag(buf + aoff + 1 * 2048 + kofs1);
    bf16x8 b00 = ldfrag(buf + boff + 0 * 2048 + kofs0);
    bf16x8 b01 = ldfrag(buf + boff + 0 * 2048 + kofs1);
    bf16x8 b10 = ldfrag(buf + boff + 1 * 2048 + kofs0);
    bf16x8 b11 = ldfrag(buf + boff + 1 * 2048 + kofs1);
    bf16x8 b20 = ldfrag(buf + boff + 2 * 2048 + kofs0);
    bf16x8 b21 = ldfrag(buf + boff + 2 * 2048 + kofs1);
    bf16x8 b30 = ldfrag(buf + boff + 3 * 2048 + kofs0);
    bf16x8 b31 = ldfrag(buf + boff + 3 * 2048 + kofs1);
    bf16x8 aB0 = ldfrag(buf + aoff + 2 * 2048 + kofs0);
    bf16x8 aB1 = ldfrag(buf + aoff + 2 * 2048 + kofs1);
    bf16x8 aB2 = ldfrag(buf + aoff + 3 * 2048 + kofs0);
    bf16x8 aB3 = ldfrag(buf + aoff + 3 * 2048 + kofs1);
    PHASE16(aA0, aA1, aA2, aA3, 0, 1);

    aA0 = ldfrag(buf + aoff + 4 * 2048 + kofs0);
    aA1 = ldfrag(buf + aoff + 4 * 2048 + kofs1);
    aA2 = ldfrag(buf + aoff + 5 * 2048 + kofs0);
    aA3 = ldfrag(buf + aoff + 5 * 2048 + kofs1);
    PHASE16(aB0, aB1, aB2, aB3, 2, 3);

    aB0 = ldfrag(buf + aoff + 6 * 2048 + kofs0);
    aB1 = ldfrag(buf + aoff + 6 * 2048 + kofs1);
    aB2 = ldfrag(buf + aoff + 7 * 2048 + kofs0);
    aB3 = ldfrag(buf + aoff + 7 * 2048 + kofs1);
    PHASE16(aA0, aA1, aA2, aA3, 4, 5);
    PHASE16(aB0, aB1, aB2, aB3, 6, 7);
  }

  // ---- epilogue: C/D layout col=lane&15, row=(lane>>4)*4+reg ----
#pragma unroll
  for (int n = 0; n < 4; ++n) {
    const int col = n0 + wn * 64 + n * 16 + lrow;
    const float bv = bias[col];
#pragma unroll
    for (int m = 0; m < 8; ++m) {
      const int row = m0 + wm * 128 + m * 16 + khi * 4;
      float* cp = C + (size_t)row * Ndim + col;
#pragma unroll
      for (int r = 0; r < 4; ++r)
        cp[(size_t)r * Ndim] = acc[m][n][r] + bv;
    }
  }
}

// ---------------- fallback: fused fp32->bf16 GEMM (no workspace) ----------------
__global__ __launch_bounds__(256) void k_gemm_fused(const float* __restrict__ A,
                                                    const float* __restrict__ B,
                                                    const float* __restrict__ bias,
                                                    float* __restrict__ C) {
  __shared__ unsigned short lA[128 * 32];
  __shared__ unsigned short lB[32 * 136];

  const int tid = threadIdx.x;
  const int wave = tid >> 6;
  const int lane = tid & 63;
  const int lrow = lane & 15;
  const int kslc = lane >> 4;
  const int wr = wave >> 1;
  const int wc = wave & 1;

  const int bid = blockIdx.x;
  const int cpx = gridDim.x >> 3;
  const int swz = (bid & 7) * cpx + (bid >> 3);
  const int m0 = (swz & 63) * 128;
  const int n0 = (swz >> 6) * 128;

  f32x4 acc[4][4];
#pragma unroll
  for (int i = 0; i < 4; ++i)
#pragma unroll
    for (int j = 0; j < 4; ++j) acc[i][j] = f32x4{0.f, 0.f, 0.f, 0.f};

  for (int k0 = 0; k0 < Kdim; k0 += 32) {
#pragma unroll
    for (int j = 0; j < 2; ++j) {
      int e = (j * 256 + tid) * 8;
      int r = e >> 5, kk = e & 31;
      const float* src = A + (size_t)(m0 + r) * Kdim + k0 + kk;
      float4 v0 = *reinterpret_cast<const float4*>(src);
      float4 v1 = *reinterpret_cast<const float4*>(src + 4);
      u16x8 o;
      o[0] = f2bf(v0.x); o[1] = f2bf(v0.y); o[2] = f2bf(v0.z); o[3] = f2bf(v0.w);
      o[4] = f2bf(v1.x); o[5] = f2bf(v1.y); o[6] = f2bf(v1.z); o[7] = f2bf(v1.w);
      *reinterpret_cast<u16x8*>(&lA[e]) = o;
    }
#pragma unroll
    for (int j = 0; j < 2; ++j) {
      int e = (j * 256 + tid) * 8;
      int r = e >> 7, c = e & 127;
      const float* src = B + (size_t)(k0 + r) * Ndim + n0 + c;
      float4 v0 = *reinterpret_cast<const float4*>(src);
      float4 v1 = *reinterpret_cast<const float4*>(src + 4);
      u16x8 o;
      o[0] = f2bf(v0.x); o[1] = f2bf(v0.y); o[2] = f2bf(v0.z); o[3] = f2bf(v0.w);
      o[4] = f2bf(v1.x); o[5] = f2bf(v1.y); o[6] = f2bf(v1.z); o[7] = f2bf(v1.w);
      *reinterpret_cast<u16x8*>(&lB[r * 136 + c]) = o;
    }
    __syncthreads();

    bf16x8 af[4], bfv[4];
#pragma unroll
    for (int m = 0; m < 4; ++m)
      af[m] = __builtin_bit_cast(
          bf16x8, *reinterpret_cast<const u16x8*>(&lA[(wr * 64 + m * 16 + lrow) * 32 + kslc * 8]));
#pragma unroll
    for (int n = 0; n < 4; ++n) {
      union { unsigned short s[8]; u16x8 v; } t;
      int col = wc * 64 + n * 16 + lrow;
#pragma unroll
      for (int i = 0; i < 8; ++i) t.s[i] = lB[(kslc * 8 + i) * 136 + col];
      bfv[n] = __builtin_bit_cast(bf16x8, t.v);
    }

#pragma unroll
    for (int m = 0; m < 4; ++m)
#pragma unroll
      for (int n = 0; n < 4; ++n)
        acc[m][n] = __builtin_amdgcn_mfma_f32_16x16x32_bf16(af[m], bfv[n], acc[m][n], 0, 0, 0);

    __syncthreads();
  }

#pragma unroll
  for (int n = 0; n < 4; ++n) {
    const int col = n0 + wc * 64 + n * 16 + lrow;
    const float bv = bias[col];
#pragma unroll
    for (int m = 0; m < 4; ++m) {
      const int row = m0 + wr * 64 + m * 16 + kslc * 4;
      float* cp = C + (size_t)row * Ndim + col;
#pragma unroll
      for (int r = 0; r < 4; ++r)
        cp[(size_t)r * Ndim] = acc[m][n][r] + bv;
    }
  }
}

extern "C" void kernel_launch(void* const* d_in, const int* in_sizes, int n_in,
                              void* d_out, int out_size, void* d_ws, size_t ws_size,
                              hipStream_t stream) {
  const float* inp = (const float*)d_in[0];
  const float* ker = (const float*)d_in[1];
  const float* bias = (const float*)d_in[2];
  float* out = (float*)d_out;

  const size_t A_BYTES = (size_t)Mdim * Kdim * 2;  // 64 MiB
  const size_t B_BYTES = (size_t)Ndim * Kdim * 2;  // 128 MiB

  if (ws_size >= A_BYTES + B_BYTES) {
    unsigned short* Abf = (unsigned short*)d_ws;
    unsigned short* Btb = (unsigned short*)((char*)d_ws + A_BYTES);
    k_convertA<<<2048, 256, 0, stream>>>(inp, Abf, Mdim * Kdim / 8);
    dim3 tg(Ndim / 64, Kdim / 64);
    k_transB<<<tg, 256, 0, stream>>>(ker, Btb);
    (void)hipFuncSetAttribute((const void*)k_gemm8,
                              hipFuncAttributeMaxDynamicSharedMemorySize, 131072);
    const int nblocks = (Mdim / 256) * (Ndim / 256);  // 2048
    k_gemm8<<<nblocks, 512, 131072, stream>>>(Abf, Btb, bias, out);
  } else {
    const int nblocks = (Mdim / 128) * (Ndim / 128);
    k_gemm_fused<<<nblocks, 256, 0, stream>>>(inp, ker, bias, out);
  }
}